// Round 14
// baseline (357.437 us; speedup 1.0000x reference)
//
#include <hip/hip_runtime.h>
#include <hip/hip_bf16.h>
#include <stdint.h>

// Problem constants
#define NB_B 2048
#define NN   64
#define DD   256
#define HH   1024
#define EE   512
#define HC   128          // H chunk size
#define NCH  (HH/HC)      // 8 chunks

typedef __attribute__((ext_vector_type(8)))  short short8;   // bf16x8 MFMA frag (4 VGPRs)
typedef __attribute__((ext_vector_type(16))) float f32x16;   // 32x32 MFMA accumulator

__device__ __forceinline__ unsigned short f2bf(float f) {
    // round-to-nearest-even f32 -> bf16
    unsigned int u = __float_as_uint(f);
    u = u + 0x7FFFu + ((u >> 16) & 1u);
    return (unsigned short)(u >> 16);
}

// Prep: emit weights in exact per-lane MFMA fragment order so that every
// weight load in the main loop is one contiguous 1 KiB wave burst.
//   w1f frag f = ((blk*16 + ks)*64 + lane), lane = g5*32 + l31:
//       elem j = W1[(ks*16 + g5*8 + j)][blk*32 + l31]      (32768 frags, 512 KiB)
//   w2f frag f = (((eblk*8 + hc)*8 + ks2)*64 + lane):
//       elem j = W2[(hc*128 + ks2*16 + g5*8 + j)][eblk*32 + l31]  (65536 frags, 1 MiB)
__global__ void prep_weights(const float* __restrict__ W1, const float* __restrict__ W2,
                             unsigned short* __restrict__ w1f, unsigned short* __restrict__ w2f) {
    int g = blockIdx.x * 512 + threadIdx.x;      // 192 blocks * 512 = 98304 exactly
    unsigned short tmp[8];
    if (g < 32768) {
        int f   = g;
        int l31 = f & 31;
        int g5  = (f >> 5) & 1;
        int ks  = (f >> 6) & 15;
        int blk = f >> 10;                        // 0..31
        int h   = blk * 32 + l31;
        int d0  = ks * 16 + g5 * 8;
        #pragma unroll
        for (int j = 0; j < 8; ++j) tmp[j] = f2bf(W1[(size_t)(d0 + j) * HH + h]);
        uint4 p;
        p.x = (unsigned int)tmp[0] | ((unsigned int)tmp[1] << 16);
        p.y = (unsigned int)tmp[2] | ((unsigned int)tmp[3] << 16);
        p.z = (unsigned int)tmp[4] | ((unsigned int)tmp[5] << 16);
        p.w = (unsigned int)tmp[6] | ((unsigned int)tmp[7] << 16);
        *(uint4*)(w1f + (size_t)f * 8) = p;
    } else {
        int f    = g - 32768;                     // 0..65535
        int l31  = f & 31;
        int g5   = (f >> 5) & 1;
        int ks2  = (f >> 6) & 7;
        int hc   = (f >> 9) & 7;
        int eblk = f >> 12;                       // 0..15
        int e    = eblk * 32 + l31;
        int h0   = hc * 128 + ks2 * 16 + g5 * 8;
        #pragma unroll
        for (int j = 0; j < 8; ++j) tmp[j] = f2bf(W2[(size_t)(h0 + j) * EE + e]);
        uint4 p;
        p.x = (unsigned int)tmp[0] | ((unsigned int)tmp[1] << 16);
        p.y = (unsigned int)tmp[2] | ((unsigned int)tmp[3] << 16);
        p.z = (unsigned int)tmp[4] | ((unsigned int)tmp[5] << 16);
        p.w = (unsigned int)tmp[6] | ((unsigned int)tmp[7] << 16);
        *(uint4*)(w2f + (size_t)f * 8) = p;
    }
}

// Fused: per-batch MLP + leave-one-out mean pooling + concat.
// grid = 2048 (one WG per batch), block = 512 (8 waves), 2 blocks/CU.
__global__ __launch_bounds__(512, 4)
void fused_mlp_loo(const float* __restrict__ X,
                   const short8* __restrict__ w1f,   // fragment-ordered W1^T bf16
                   const short8* __restrict__ w2f,   // fragment-ordered W2^T bf16
                   const float* __restrict__ b1,
                   const float* __restrict__ b2,
                   float* __restrict__ out)
{
    // Xs:   [64][256] bf16, row stride 512B, offset 0       (32 KiB, XOR-swizzled)
    // Hs[j]:[64][128] bf16, row stride 256B, offset 32768+j*16384  (2 x 16 KiB, double buffer)
    // Bs:   b1 copy, 1024 f32, offset 65536                 (4 KiB)
    __shared__ __attribute__((aligned(16))) unsigned char lds[69632];

    const int bid = blockIdx.x;
    const int tid = threadIdx.x;
    const int w   = tid >> 6;    // wave 0..7
    const int l   = tid & 63;
    const int g5  = l >> 5;      // 0/1
    const int l31 = l & 31;
    const int wh  = w >> 1;      // GEMM1 hcol group 0..3
    const int wx  = w & 1;       // GEMM1 xrow group 0..1

    // ---- stage b1 into LDS ----
    {
        float2 v = *(const float2*)(b1 + tid * 2);
        *(float2*)(lds + 65536 + tid * 8) = v;
    }
    // ---- stage X (f32 -> bf16, XOR-swizzled) + copy inputs to out[..., 0:256] ----
    {
        const float4* Xv = (const float4*)(X + (size_t)bid * (NN * DD));
        #pragma unroll
        for (int k = 0; k < 8; ++k) {
            int f = tid + k * 512;           // float4 index in [0,4096)
            float4 v = Xv[f];                // fully coalesced
            int row = f >> 6;                // 0..63
            int c4  = f & 63;                // float4 within row
            uint2 p;
            p.x = (unsigned int)f2bf(v.x) | ((unsigned int)f2bf(v.y) << 16);
            p.y = (unsigned int)f2bf(v.z) | ((unsigned int)f2bf(v.w) << 16);
            int off = (c4 * 8) ^ ((row & 15) << 4);
            *(uint2*)(lds + row * 512 + off) = p;
            float4* ov = (float4*)(out + (size_t)(bid * NN + row) * (DD + EE));
            ov[c4] = v;                      // input copy (exact f32)
        }
    }
    __syncthreads();

    const int xrow = 32 * wx + l31;
    const unsigned char* xbase = lds + xrow * 512;
    const int xswz = (xrow & 15) << 4;

    f32x16 acc[2][2] = {};   // emb accumulators: wave owns rows 0..63 x cols [64w, 64w+64)

    // GEMM1 for chunk hc (prologue only): c1 = h^T chunk
    auto gemm1_compute = [&](int hc, f32x16& c1) {
        const short8* a1p = w1f + (size_t)((hc * 4 + wh) * 16) * 64 + l;
        #pragma unroll
        for (int ks = 0; ks < 16; ++ks) {
            short8 a1 = a1p[ks * 64];      // contiguous 1 KiB wave burst
            short8 xb = *(const short8*)(xbase + ((ks * 32 + 16 * g5) ^ xswz));
            c1 = __builtin_amdgcn_mfma_f32_32x32x16_bf16(a1, xb, c1, 0, 0, 0);
        }
    };

    // Fused step: gemm1(hc_next) interleaved with gemm2(hc_cur).
    // Per ks2: 2 chained c1 MFMAs separated by 2 independent acc MFMAs each ->
    // c1 dependence distance = 3 MFMA slots; 3 independent load->MFMA streams.
    auto fused_step = [&](int hc_next, int hc_cur, f32x16& c1) {
        const short8* a1p = w1f + (size_t)((hc_next * 4 + wh) * 16) * 64 + l;
        const unsigned char* hrd = lds + 32768 + (hc_cur & 1) * 16384;
        const short8* b0p = w2f + (size_t)(((2 * w + 0) * 8 + hc_cur) * 8) * 64 + l;
        const short8* b1p = w2f + (size_t)(((2 * w + 1) * 8 + hc_cur) * 8) * 64 + l;
        #pragma unroll
        for (int ks2 = 0; ks2 < 8; ++ks2) {
            int ksa = 2 * ks2, ksb = 2 * ks2 + 1;
            short8 a1a = a1p[ksa * 64];
            short8 xba = *(const short8*)(xbase + ((ksa * 32 + 16 * g5) ^ xswz));
            short8 bw0 = b0p[ks2 * 64];
            short8 bw1 = b1p[ks2 * 64];
            short8 a20 = *(const short8*)(hrd + l31 * 256 +
                                          ((32 * ks2 + 16 * g5) ^ ((l31 & 15) << 4)));
            c1 = __builtin_amdgcn_mfma_f32_32x32x16_bf16(a1a, xba, c1, 0, 0, 0);
            acc[0][0] = __builtin_amdgcn_mfma_f32_32x32x16_bf16(a20, bw0, acc[0][0], 0, 0, 0);
            acc[0][1] = __builtin_amdgcn_mfma_f32_32x32x16_bf16(a20, bw1, acc[0][1], 0, 0, 0);
            short8 a1b = a1p[ksb * 64];
            short8 xbb = *(const short8*)(xbase + ((ksb * 32 + 16 * g5) ^ xswz));
            short8 a21 = *(const short8*)(hrd + (32 + l31) * 256 +
                                          ((32 * ks2 + 16 * g5) ^ ((l31 & 15) << 4)));
            c1 = __builtin_amdgcn_mfma_f32_32x32x16_bf16(a1b, xbb, c1, 0, 0, 0);
            acc[1][0] = __builtin_amdgcn_mfma_f32_32x32x16_bf16(a21, bw0, acc[1][0], 0, 0, 0);
            acc[1][1] = __builtin_amdgcn_mfma_f32_32x32x16_bf16(a21, bw1, acc[1][1], 0, 0, 0);
        }
    };

    // bias + relu + pack h chunk into Hs[hc&1]
    auto pack_h = [&](int hc, const f32x16& c1) {
        unsigned char* hbase = lds + 32768 + (hc & 1) * 16384 + xrow * 256;
        const int hswz = (xrow & 15) << 4;
        const float* Bs = (const float*)(lds + 65536);
        #pragma unroll
        for (int q = 0; q < 4; ++q) {
            float4 bb = *(const float4*)(Bs + hc * HC + 32 * wh + 4 * g5 + 8 * q);
            float v0 = fmaxf(c1[4 * q + 0] + bb.x, 0.f);
            float v1 = fmaxf(c1[4 * q + 1] + bb.y, 0.f);
            float v2 = fmaxf(c1[4 * q + 2] + bb.z, 0.f);
            float v3 = fmaxf(c1[4 * q + 3] + bb.w, 0.f);
            uint2 p;
            p.x = (unsigned int)f2bf(v0) | ((unsigned int)f2bf(v1) << 16);
            p.y = (unsigned int)f2bf(v2) | ((unsigned int)f2bf(v3) << 16);
            int off = (64 * wh + 16 * q + 8 * g5) ^ hswz;
            *(uint2*)(hbase + off) = p;
        }
    };

    // GEMM2 accumulate chunk hc (epilogue only, no gemm1 partner)
    auto gemm2_step = [&](int hc) {
        const unsigned char* hrd = lds + 32768 + (hc & 1) * 16384;
        const short8* b0p = w2f + (size_t)(((2 * w + 0) * 8 + hc) * 8) * 64 + l;
        const short8* b1p = w2f + (size_t)(((2 * w + 1) * 8 + hc) * 8) * 64 + l;
        #pragma unroll
        for (int ks2 = 0; ks2 < 8; ++ks2) {
            short8 a2[2];
            #pragma unroll
            for (int mf = 0; mf < 2; ++mf) {
                int row = 32 * mf + l31;
                a2[mf] = *(const short8*)(hrd + row * 256 +
                                          ((32 * ks2 + 16 * g5) ^ ((row & 15) << 4)));
            }
            short8 bw0 = b0p[ks2 * 64];
            short8 bw1 = b1p[ks2 * 64];
            acc[0][0] = __builtin_amdgcn_mfma_f32_32x32x16_bf16(a2[0], bw0, acc[0][0], 0, 0, 0);
            acc[0][1] = __builtin_amdgcn_mfma_f32_32x32x16_bf16(a2[0], bw1, acc[0][1], 0, 0, 0);
            acc[1][0] = __builtin_amdgcn_mfma_f32_32x32x16_bf16(a2[1], bw0, acc[1][0], 0, 0, 0);
            acc[1][1] = __builtin_amdgcn_mfma_f32_32x32x16_bf16(a2[1], bw1, acc[1][1], 0, 0, 0);
        }
    };

    // ---- software-pipelined main loop: one barrier per chunk ----
    {
        f32x16 c1 = {};
        gemm1_compute(0, c1);
        pack_h(0, c1);
    }
    __syncthreads();

    for (int i = 0; i < NCH - 1; ++i) {
        f32x16 c1 = {};
        fused_step(i + 1, i, c1);    // gemm1(i+1) MFMAs interleaved with gemm2(i)
        pack_h(i + 1, c1);
        __syncthreads();
    }
    gemm2_step(NCH - 1);

    // ---- epilogue: in-register LOO. Wave owns all 64 rows of its 64 cols. ----
    float tsum[2];
    #pragma unroll
    for (int nf = 0; nf < 2; ++nf) {
        float s = 0.f;
        #pragma unroll
        for (int mf = 0; mf < 2; ++mf)
            #pragma unroll
            for (int r = 0; r < 16; ++r)
                s += acc[mf][nf][r];
        s += __shfl_xor(s, 32, 64);    // combine the two lane halves -> full 64-row column sum
        tsum[nf] = s;
    }
    const float b2c0 = b2[64 * w + l31];
    const float b2c1 = b2[64 * w + 32 + l31];
    const float inv63 = 1.0f / 63.0f;
    float* obase = out + (size_t)bid * NN * (DD + EE) + DD;
    #pragma unroll
    for (int mf = 0; mf < 2; ++mf) {
        #pragma unroll
        for (int r = 0; r < 16; ++r) {
            int row = 32 * mf + (r & 3) + 8 * (r >> 2) + 4 * g5;
            float* orow = obase + (size_t)row * (DD + EE);
            {
                float raw = acc[mf][0][r];
                orow[64 * w + l31] = (tsum[0] - raw) * inv63 + b2c0;
            }
            {
                float raw = acc[mf][1][r];
                orow[64 * w + 32 + l31] = (tsum[1] - raw) * inv63 + b2c1;
            }
        }
    }
}

extern "C" void kernel_launch(void* const* d_in, const int* in_sizes, int n_in,
                              void* d_out, int out_size, void* d_ws, size_t ws_size,
                              hipStream_t stream) {
    const float* X  = (const float*)d_in[0];
    const float* W1 = (const float*)d_in[1];
    const float* b1 = (const float*)d_in[2];
    const float* W2 = (const float*)d_in[3];
    const float* b2 = (const float*)d_in[4];
    float* out = (float*)d_out;

    unsigned short* w1f = (unsigned short*)d_ws;             // 32768 frags * 16B = 512 KiB
    unsigned short* w2f = w1f + (size_t)32768 * 8;           // 65536 frags * 16B = 1 MiB

    prep_weights<<<192, 512, 0, stream>>>(W1, W2, w1f, w2f);
    fused_mlp_loo<<<NB_B, 512, 0, stream>>>(X, (const short8*)w1f, (const short8*)w2f,
                                            b1, b2, out);
}

// Round 15
// 305.858 us; speedup vs baseline: 1.1686x; 1.1686x over previous
//
#include <hip/hip_runtime.h>
#include <hip/hip_bf16.h>
#include <stdint.h>

// Problem constants
#define NB_B 2048
#define NN   64
#define DD   256
#define HH   1024
#define EE   512
#define HC   128          // H chunk size
#define NCH  (HH/HC)      // 8 chunks

typedef __attribute__((ext_vector_type(8)))  short short8;   // bf16x8 MFMA frag (4 VGPRs)
typedef __attribute__((ext_vector_type(16))) float f32x16;   // 32x32 MFMA accumulator

#define W2SCALE 32.0f     // W2 pre-scaled into e4m3 sweet spot; undone in epilogue

__device__ __forceinline__ unsigned short f2bf(float f) {
    // round-to-nearest-even f32 -> bf16
    unsigned int u = __float_as_uint(f);
    u = u + 0x7FFFu + ((u >> 16) & 1u);
    return (unsigned short)(u >> 16);
}

// Prep: weights in exact per-lane MFMA fragment order.
//   w1f (bf16, 16B/lane): frag f = ((blk*16 + ks)*64 + lane), lane = g5*32 + l31:
//       elem j = W1[(ks*16 + g5*8 + j)][blk*32 + l31]          (32768 frags, 512 KiB)
//   w2f8 (fp8 e4m3 scaled x32, 8B/lane): frag f = (((eblk*8 + hc)*8 + ks2)*64 + lane):
//       elem j = 32*W2[(hc*128 + ks2*16 + g5*8 + j)][eblk*32 + l31]  (65536 frags, 512 KiB)
__global__ void prep_weights(const float* __restrict__ W1, const float* __restrict__ W2,
                             unsigned short* __restrict__ w1f, int* __restrict__ w2f8) {
    int g = blockIdx.x * 512 + threadIdx.x;      // 192 blocks * 512 = 98304 exactly
    if (g < 32768) {
        int f   = g;
        int l31 = f & 31;
        int g5  = (f >> 5) & 1;
        int ks  = (f >> 6) & 15;
        int blk = f >> 10;                        // 0..31
        int h   = blk * 32 + l31;
        int d0  = ks * 16 + g5 * 8;
        unsigned short tmp[8];
        #pragma unroll
        for (int j = 0; j < 8; ++j) tmp[j] = f2bf(W1[(size_t)(d0 + j) * HH + h]);
        uint4 p;
        p.x = (unsigned int)tmp[0] | ((unsigned int)tmp[1] << 16);
        p.y = (unsigned int)tmp[2] | ((unsigned int)tmp[3] << 16);
        p.z = (unsigned int)tmp[4] | ((unsigned int)tmp[5] << 16);
        p.w = (unsigned int)tmp[6] | ((unsigned int)tmp[7] << 16);
        *(uint4*)(w1f + (size_t)f * 8) = p;
    } else {
        int f    = g - 32768;                     // 0..65535
        int l31  = f & 31;
        int g5   = (f >> 5) & 1;
        int ks2  = (f >> 6) & 7;
        int hc   = (f >> 9) & 7;
        int eblk = f >> 12;                       // 0..15
        int e    = eblk * 32 + l31;
        int h0   = hc * 128 + ks2 * 16 + g5 * 8;
        float t[8];
        #pragma unroll
        for (int j = 0; j < 8; ++j) t[j] = W2[(size_t)(h0 + j) * EE + e] * W2SCALE;
        int lo = __builtin_amdgcn_cvt_pk_fp8_f32(t[0], t[1], 0, false);
        lo     = __builtin_amdgcn_cvt_pk_fp8_f32(t[2], t[3], lo, true);
        int hi = __builtin_amdgcn_cvt_pk_fp8_f32(t[4], t[5], 0, false);
        hi     = __builtin_amdgcn_cvt_pk_fp8_f32(t[6], t[7], hi, true);
        w2f8[(size_t)f * 2]     = lo;
        w2f8[(size_t)f * 2 + 1] = hi;
    }
}

// Fused: per-batch MLP + leave-one-out mean pooling + concat.
// grid = 2048 (one WG per batch), block = 512 (8 waves), 2 blocks/CU.
// GEMM1 in bf16; GEMM2 in fp8 e4m3 (W2 scaled x32, h in [0, ~6] fits e4m3 well).
__global__ __launch_bounds__(512, 4)
void fused_mlp_loo(const float* __restrict__ X,
                   const short8* __restrict__ w1f,        // fragment-ordered W1^T bf16
                   const long long* __restrict__ w2f8,    // fragment-ordered W2^T fp8 (x32)
                   const float* __restrict__ b1,
                   const float* __restrict__ b2,
                   float* __restrict__ out)
{
    // Xs:   [64][256] bf16, row stride 512B, offset 0      (32 KiB, XOR-swizzled)
    // Hs[j]:[64][128] fp8, row stride 128B, offset 32768+j*8192  (2 x 8 KiB, double buffer)
    // Bs:   b1 copy, 1024 f32, offset 49152                (4 KiB)
    __shared__ __attribute__((aligned(16))) unsigned char lds[53248];

    const int bid = blockIdx.x;
    const int tid = threadIdx.x;
    const int w   = tid >> 6;    // wave 0..7
    const int l   = tid & 63;
    const int g5  = l >> 5;      // 0/1
    const int l31 = l & 31;
    const int wh  = w >> 1;      // GEMM1 hcol group 0..3
    const int wx  = w & 1;       // GEMM1 xrow group 0..1

    // ---- stage b1 into LDS ----
    {
        float2 v = *(const float2*)(b1 + tid * 2);
        *(float2*)(lds + 49152 + tid * 8) = v;
    }
    // ---- stage X (f32 -> bf16, XOR-swizzled) + copy inputs to out[..., 0:256] ----
    {
        const float4* Xv = (const float4*)(X + (size_t)bid * (NN * DD));
        #pragma unroll
        for (int k = 0; k < 8; ++k) {
            int f = tid + k * 512;           // float4 index in [0,4096)
            float4 v = Xv[f];                // fully coalesced
            int row = f >> 6;                // 0..63
            int c4  = f & 63;                // float4 within row
            uint2 p;
            p.x = (unsigned int)f2bf(v.x) | ((unsigned int)f2bf(v.y) << 16);
            p.y = (unsigned int)f2bf(v.z) | ((unsigned int)f2bf(v.w) << 16);
            int off = (c4 * 8) ^ ((row & 15) << 4);
            *(uint2*)(lds + row * 512 + off) = p;
            float4* ov = (float4*)(out + (size_t)(bid * NN + row) * (DD + EE));
            ov[c4] = v;                      // input copy (exact f32)
        }
    }
    __syncthreads();

    const int xrow = 32 * wx + l31;
    const unsigned char* xbase = lds + xrow * 512;
    const int xswz = (xrow & 15) << 4;

    f32x16 acc[2][2] = {};   // emb accumulators (scaled x32): rows 0..63 x cols [64w, 64w+64)

    // GEMM1 for chunk hc: c1 = h^T chunk (A = w1f frag, B = Xs frag), bf16
    auto gemm1_compute = [&](int hc, f32x16& c1) {
        const short8* a1p = w1f + (size_t)((hc * 4 + wh) * 16) * 64 + l;
        #pragma unroll
        for (int ks = 0; ks < 16; ++ks) {
            short8 a1 = a1p[ks * 64];      // contiguous 1 KiB wave burst
            short8 xb = *(const short8*)(xbase + ((ks * 32 + 16 * g5) ^ xswz));
            c1 = __builtin_amdgcn_mfma_f32_32x32x16_bf16(a1, xb, c1, 0, 0, 0);
        }
    };

    // bias + relu + pack h chunk into Hs[hc&1] as fp8 e4m3.
    // h[xrow][col], col = 32wh + 8q + 4g5 + {0..3}; byte off = col ^ ((xrow&15)<<3)
    auto pack_h = [&](int hc, const f32x16& c1) {
        unsigned char* hbase = lds + 32768 + (hc & 1) * 8192 + xrow * 128;
        const int hswz = (xrow & 15) << 3;
        const float* Bs = (const float*)(lds + 49152);
        #pragma unroll
        for (int q = 0; q < 4; ++q) {
            float4 bb = *(const float4*)(Bs + hc * HC + 32 * wh + 4 * g5 + 8 * q);
            float v0 = fmaxf(c1[4 * q + 0] + bb.x, 0.f);
            float v1 = fmaxf(c1[4 * q + 1] + bb.y, 0.f);
            float v2 = fmaxf(c1[4 * q + 2] + bb.z, 0.f);
            float v3 = fmaxf(c1[4 * q + 3] + bb.w, 0.f);
            int pk = __builtin_amdgcn_cvt_pk_fp8_f32(v0, v1, 0, false);
            pk     = __builtin_amdgcn_cvt_pk_fp8_f32(v2, v3, pk, true);
            *(int*)(hbase + ((32 * wh + 8 * q + 4 * g5) ^ hswz)) = pk;
        }
    };

    // GEMM2 accumulate chunk hc in fp8: acc += Hs[hc&1] @ w2f8[chunk,:]
    auto gemm2_step = [&](int hc) {
        const unsigned char* hrd = lds + 32768 + (hc & 1) * 8192;
        const long long* b0p = w2f8 + (size_t)(((2 * w + 0) * 8 + hc) * 8) * 64 + l;
        const long long* b1p = w2f8 + (size_t)(((2 * w + 1) * 8 + hc) * 8) * 64 + l;
        #pragma unroll
        for (int ks2 = 0; ks2 < 8; ++ks2) {
            long long a2[2];
            #pragma unroll
            for (int mf = 0; mf < 2; ++mf) {
                int row = 32 * mf + l31;
                a2[mf] = *(const long long*)(hrd + row * 128 +
                                             ((ks2 * 16 + 8 * g5) ^ ((row & 15) << 3)));
            }
            long long bw0 = b0p[ks2 * 64];    // contiguous 512B wave bursts
            long long bw1 = b1p[ks2 * 64];
            acc[0][0] = __builtin_amdgcn_mfma_f32_32x32x16_fp8_fp8(a2[0], bw0, acc[0][0], 0, 0, 0);
            acc[0][1] = __builtin_amdgcn_mfma_f32_32x32x16_fp8_fp8(a2[0], bw1, acc[0][1], 0, 0, 0);
            acc[1][0] = __builtin_amdgcn_mfma_f32_32x32x16_fp8_fp8(a2[1], bw0, acc[1][0], 0, 0, 0);
            acc[1][1] = __builtin_amdgcn_mfma_f32_32x32x16_fp8_fp8(a2[1], bw1, acc[1][1], 0, 0, 0);
        }
    };

    // ---- software-pipelined main loop: one barrier per chunk ----
    {
        f32x16 c1 = {};
        gemm1_compute(0, c1);
        pack_h(0, c1);
    }
    __syncthreads();

    for (int i = 0; i < NCH - 1; ++i) {
        // produce chunk i+1 (long-latency weight loads) interleaved with consuming chunk i
        f32x16 c1 = {};
        gemm1_compute(i + 1, c1);
        gemm2_step(i);
        pack_h(i + 1, c1);
        __syncthreads();
    }
    gemm2_step(NCH - 1);

    // ---- epilogue: in-register LOO (acc carries x32 scale; undo here) ----
    float tsum[2];
    #pragma unroll
    for (int nf = 0; nf < 2; ++nf) {
        float s = 0.f;
        #pragma unroll
        for (int mf = 0; mf < 2; ++mf)
            #pragma unroll
            for (int r = 0; r < 16; ++r)
                s += acc[mf][nf][r];
        s += __shfl_xor(s, 32, 64);    // combine the two lane halves -> full 64-row column sum
        tsum[nf] = s;
    }
    const float b2c0 = b2[64 * w + l31];
    const float b2c1 = b2[64 * w + 32 + l31];
    const float sc = 1.0f / (63.0f * W2SCALE);
    float* obase = out + (size_t)bid * NN * (DD + EE) + DD;
    #pragma unroll
    for (int mf = 0; mf < 2; ++mf) {
        #pragma unroll
        for (int r = 0; r < 16; ++r) {
            int row = 32 * mf + (r & 3) + 8 * (r >> 2) + 4 * g5;
            float* orow = obase + (size_t)row * (DD + EE);
            {
                float raw = acc[mf][0][r];
                orow[64 * w + l31] = (tsum[0] - raw) * sc + b2c0;
            }
            {
                float raw = acc[mf][1][r];
                orow[64 * w + 32 + l31] = (tsum[1] - raw) * sc + b2c1;
            }
        }
    }
}

extern "C" void kernel_launch(void* const* d_in, const int* in_sizes, int n_in,
                              void* d_out, int out_size, void* d_ws, size_t ws_size,
                              hipStream_t stream) {
    const float* X  = (const float*)d_in[0];
    const float* W1 = (const float*)d_in[1];
    const float* b1 = (const float*)d_in[2];
    const float* W2 = (const float*)d_in[3];
    const float* b2 = (const float*)d_in[4];
    float* out = (float*)d_out;

    unsigned short* w1f = (unsigned short*)d_ws;             // 32768 frags * 16B = 512 KiB
    int* w2f8 = (int*)(w1f + (size_t)32768 * 8);             // 65536 frags * 8B = 512 KiB

    prep_weights<<<192, 512, 0, stream>>>(W1, W2, w1f, w2f8);
    fused_mlp_loo<<<NB_B, 512, 0, stream>>>(X, (const short8*)w1f, (const long long*)w2f8,
                                            b1, b2, out);
}

// Round 16
// 298.979 us; speedup vs baseline: 1.1955x; 1.0230x over previous
//
#include <hip/hip_runtime.h>
#include <hip/hip_bf16.h>
#include <stdint.h>

// Problem constants
#define NB_B 2048
#define NN   64
#define DD   256
#define HH   1024
#define EE   512
#define HC   128          // H chunk size
#define NCH  (HH/HC)      // 8 chunks

typedef __attribute__((ext_vector_type(16))) float f32x16;   // 32x32 MFMA accumulator

#define W1SCALE 32.0f     // W1 pre-scaled into e4m3 range; undone in pack_h bias-add
#define W2SCALE 32.0f     // W2 pre-scaled into e4m3 range; undone in epilogue

// Prep: weights in exact per-lane MFMA fragment order, both fp8 e4m3.
//   w1f8 (8B/lane): frag f = ((blk*16 + ks)*64 + lane), lane = g5*32 + l31:
//       byte j = fp8(32*W1[(ks*16 + g5*8 + j)][blk*32 + l31])     (32768 frags, 256 KiB)
//   w2f8 (8B/lane): frag f = (((eblk*8 + hc)*8 + ks2)*64 + lane):
//       byte j = fp8(32*W2[(hc*128 + ks2*16 + g5*8 + j)][eblk*32 + l31])  (65536 frags, 512 KiB)
__global__ void prep_weights(const float* __restrict__ W1, const float* __restrict__ W2,
                             int* __restrict__ w1f8, int* __restrict__ w2f8) {
    int g = blockIdx.x * 512 + threadIdx.x;      // 192 blocks * 512 = 98304 exactly
    if (g < 32768) {
        int f   = g;
        int l31 = f & 31;
        int g5  = (f >> 5) & 1;
        int ks  = (f >> 6) & 15;
        int blk = f >> 10;                        // 0..31
        int h   = blk * 32 + l31;
        int d0  = ks * 16 + g5 * 8;
        float t[8];
        #pragma unroll
        for (int j = 0; j < 8; ++j) t[j] = W1[(size_t)(d0 + j) * HH + h] * W1SCALE;
        int lo = __builtin_amdgcn_cvt_pk_fp8_f32(t[0], t[1], 0, false);
        lo     = __builtin_amdgcn_cvt_pk_fp8_f32(t[2], t[3], lo, true);
        int hi = __builtin_amdgcn_cvt_pk_fp8_f32(t[4], t[5], 0, false);
        hi     = __builtin_amdgcn_cvt_pk_fp8_f32(t[6], t[7], hi, true);
        w1f8[(size_t)f * 2]     = lo;
        w1f8[(size_t)f * 2 + 1] = hi;
    } else {
        int f    = g - 32768;                     // 0..65535
        int l31  = f & 31;
        int g5   = (f >> 5) & 1;
        int ks2  = (f >> 6) & 7;
        int hc   = (f >> 9) & 7;
        int eblk = f >> 12;                       // 0..15
        int e    = eblk * 32 + l31;
        int h0   = hc * 128 + ks2 * 16 + g5 * 8;
        float t[8];
        #pragma unroll
        for (int j = 0; j < 8; ++j) t[j] = W2[(size_t)(h0 + j) * EE + e] * W2SCALE;
        int lo = __builtin_amdgcn_cvt_pk_fp8_f32(t[0], t[1], 0, false);
        lo     = __builtin_amdgcn_cvt_pk_fp8_f32(t[2], t[3], lo, true);
        int hi = __builtin_amdgcn_cvt_pk_fp8_f32(t[4], t[5], 0, false);
        hi     = __builtin_amdgcn_cvt_pk_fp8_f32(t[6], t[7], hi, true);
        w2f8[(size_t)f * 2]     = lo;
        w2f8[(size_t)f * 2 + 1] = hi;
    }
}

// Fused: per-batch MLP + leave-one-out mean pooling + concat.
// grid = 2048 (one WG per batch), block = 512 (8 waves), 2 blocks/CU.
// Both GEMMs in fp8 e4m3 (weights scaled x32; LOO's sqrt(63) error averaging
// keeps output absmax ~0.07 << 0.108 threshold).
__global__ __launch_bounds__(512, 4)
void fused_mlp_loo(const float* __restrict__ X,
                   const long long* __restrict__ w1f8,    // fragment-ordered W1^T fp8 (x32)
                   const long long* __restrict__ w2f8,    // fragment-ordered W2^T fp8 (x32)
                   const float* __restrict__ b1,
                   const float* __restrict__ b2,
                   float* __restrict__ out)
{
    // Xs:   [64][256] fp8, row stride 256B, offset 0      (16 KiB, XOR-swizzled by 8B granule)
    // Hs[j]:[64][128] fp8, row stride 128B, offset 16384+j*8192  (2 x 8 KiB, double buffer)
    // Bs:   b1 copy, 1024 f32, offset 32768               (4 KiB)
    __shared__ __attribute__((aligned(16))) unsigned char lds[36864];

    const int bid = blockIdx.x;
    const int tid = threadIdx.x;
    const int w   = tid >> 6;    // wave 0..7
    const int l   = tid & 63;
    const int g5  = l >> 5;      // 0/1
    const int l31 = l & 31;
    const int wh  = w >> 1;      // GEMM1 hcol group 0..3
    const int wx  = w & 1;       // GEMM1 xrow group 0..1

    // ---- stage b1 into LDS ----
    {
        float2 v = *(const float2*)(b1 + tid * 2);
        *(float2*)(lds + 32768 + tid * 8) = v;
    }
    // ---- stage X (f32 -> fp8, XOR-swizzled) + copy inputs to out[..., 0:256] ----
    {
        const float4* Xv = (const float4*)(X + (size_t)bid * (NN * DD));
        #pragma unroll
        for (int k = 0; k < 8; ++k) {
            int f = tid + k * 512;           // float4 index in [0,4096)
            float4 v = Xv[f];                // fully coalesced
            int row = f >> 6;                // 0..63
            int c4  = f & 63;                // float4 within row
            int pk = __builtin_amdgcn_cvt_pk_fp8_f32(v.x, v.y, 0, false);
            pk     = __builtin_amdgcn_cvt_pk_fp8_f32(v.z, v.w, pk, true);
            int off = (c4 * 4) ^ ((row & 15) << 3);
            *(int*)(lds + row * 256 + off) = pk;
            float4* ov = (float4*)(out + (size_t)(bid * NN + row) * (DD + EE));
            ov[c4] = v;                      // input copy (exact f32)
        }
    }
    __syncthreads();

    const int xrow = 32 * wx + l31;
    const unsigned char* xbase = lds + xrow * 256;
    const int xswz = (xrow & 15) << 3;

    f32x16 acc[2][2] = {};   // emb accumulators (scaled x32): rows 0..63 x cols [64w, 64w+64)

    // GEMM1 for chunk hc: c1 = 32 * h^T chunk (A = w1f8 frag, B = Xs frag), fp8
    auto gemm1_compute = [&](int hc, f32x16& c1) {
        const long long* a1p = w1f8 + (size_t)((hc * 4 + wh) * 16) * 64 + l;
        #pragma unroll
        for (int ks = 0; ks < 16; ++ks) {
            long long a1 = a1p[ks * 64];   // contiguous 512B wave burst
            long long xb = *(const long long*)(xbase + ((ks * 16 + 8 * g5) ^ xswz));
            c1 = __builtin_amdgcn_mfma_f32_32x32x16_fp8_fp8(a1, xb, c1, 0, 0, 0);
        }
    };

    // bias + relu + pack h chunk into Hs[hc&1] as fp8 e4m3 (h = c1/32 + b1).
    auto pack_h = [&](int hc, const f32x16& c1) {
        unsigned char* hbase = lds + 16384 + (hc & 1) * 8192 + xrow * 128;
        const int hswz = (xrow & 15) << 3;
        const float* Bs = (const float*)(lds + 32768);
        const float is = 1.0f / W1SCALE;
        #pragma unroll
        for (int q = 0; q < 4; ++q) {
            float4 bb = *(const float4*)(Bs + hc * HC + 32 * wh + 4 * g5 + 8 * q);
            float v0 = fmaxf(fmaf(c1[4 * q + 0], is, bb.x), 0.f);
            float v1 = fmaxf(fmaf(c1[4 * q + 1], is, bb.y), 0.f);
            float v2 = fmaxf(fmaf(c1[4 * q + 2], is, bb.z), 0.f);
            float v3 = fmaxf(fmaf(c1[4 * q + 3], is, bb.w), 0.f);
            int pk = __builtin_amdgcn_cvt_pk_fp8_f32(v0, v1, 0, false);
            pk     = __builtin_amdgcn_cvt_pk_fp8_f32(v2, v3, pk, true);
            *(int*)(hbase + ((32 * wh + 8 * q + 4 * g5) ^ hswz)) = pk;
        }
    };

    // GEMM2 accumulate chunk hc in fp8: acc += Hs[hc&1] @ w2f8[chunk,:]
    auto gemm2_step = [&](int hc) {
        const unsigned char* hrd = lds + 16384 + (hc & 1) * 8192;
        const long long* b0p = w2f8 + (size_t)(((2 * w + 0) * 8 + hc) * 8) * 64 + l;
        const long long* b1p = w2f8 + (size_t)(((2 * w + 1) * 8 + hc) * 8) * 64 + l;
        #pragma unroll
        for (int ks2 = 0; ks2 < 8; ++ks2) {
            long long a2[2];
            #pragma unroll
            for (int mf = 0; mf < 2; ++mf) {
                int row = 32 * mf + l31;
                a2[mf] = *(const long long*)(hrd + row * 128 +
                                             ((ks2 * 16 + 8 * g5) ^ ((row & 15) << 3)));
            }
            long long bw0 = b0p[ks2 * 64];    // contiguous 512B wave bursts
            long long bw1 = b1p[ks2 * 64];
            acc[0][0] = __builtin_amdgcn_mfma_f32_32x32x16_fp8_fp8(a2[0], bw0, acc[0][0], 0, 0, 0);
            acc[0][1] = __builtin_amdgcn_mfma_f32_32x32x16_fp8_fp8(a2[0], bw1, acc[0][1], 0, 0, 0);
            acc[1][0] = __builtin_amdgcn_mfma_f32_32x32x16_fp8_fp8(a2[1], bw0, acc[1][0], 0, 0, 0);
            acc[1][1] = __builtin_amdgcn_mfma_f32_32x32x16_fp8_fp8(a2[1], bw1, acc[1][1], 0, 0, 0);
        }
    };

    // ---- software-pipelined main loop: one barrier per chunk ----
    {
        f32x16 c1 = {};
        gemm1_compute(0, c1);
        pack_h(0, c1);
    }
    __syncthreads();

    for (int i = 0; i < NCH - 1; ++i) {
        // produce chunk i+1 (long-latency weight loads) interleaved with consuming chunk i
        f32x16 c1 = {};
        gemm1_compute(i + 1, c1);
        gemm2_step(i);
        pack_h(i + 1, c1);
        __syncthreads();
    }
    gemm2_step(NCH - 1);

    // ---- epilogue: in-register LOO (acc carries x32 scale from W2; undo here) ----
    float tsum[2];
    #pragma unroll
    for (int nf = 0; nf < 2; ++nf) {
        float s = 0.f;
        #pragma unroll
        for (int mf = 0; mf < 2; ++mf)
            #pragma unroll
            for (int r = 0; r < 16; ++r)
                s += acc[mf][nf][r];
        s += __shfl_xor(s, 32, 64);    // combine the two lane halves -> full 64-row column sum
        tsum[nf] = s;
    }
    const float b2c0 = b2[64 * w + l31];
    const float b2c1 = b2[64 * w + 32 + l31];
    const float sc = 1.0f / (63.0f * W2SCALE);
    float* obase = out + (size_t)bid * NN * (DD + EE) + DD;
    #pragma unroll
    for (int mf = 0; mf < 2; ++mf) {
        #pragma unroll
        for (int r = 0; r < 16; ++r) {
            int row = 32 * mf + (r & 3) + 8 * (r >> 2) + 4 * g5;
            float* orow = obase + (size_t)row * (DD + EE);
            {
                float raw = acc[mf][0][r];
                orow[64 * w + l31] = (tsum[0] - raw) * sc + b2c0;
            }
            {
                float raw = acc[mf][1][r];
                orow[64 * w + 32 + l31] = (tsum[1] - raw) * sc + b2c1;
            }
        }
    }
}

extern "C" void kernel_launch(void* const* d_in, const int* in_sizes, int n_in,
                              void* d_out, int out_size, void* d_ws, size_t ws_size,
                              hipStream_t stream) {
    const float* X  = (const float*)d_in[0];
    const float* W1 = (const float*)d_in[1];
    const float* b1 = (const float*)d_in[2];
    const float* W2 = (const float*)d_in[3];
    const float* b2 = (const float*)d_in[4];
    float* out = (float*)d_out;

    int* w1f8 = (int*)d_ws;                                  // 32768 frags * 8B = 256 KiB
    int* w2f8 = w1f8 + (size_t)32768 * 2;                    // 65536 frags * 8B = 512 KiB

    prep_weights<<<192, 512, 0, stream>>>(W1, W2, w1f8, w2f8);
    fused_mlp_loo<<<NB_B, 512, 0, stream>>>(X, (const long long*)w1f8, (const long long*)w2f8,
                                            b1, b2, out);
}

// Round 17
// 254.880 us; speedup vs baseline: 1.4024x; 1.1730x over previous
//
#include <hip/hip_runtime.h>
#include <hip/hip_bf16.h>
#include <stdint.h>

// Problem constants
#define NB_B 2048
#define NN   64
#define DD   256
#define HH   1024
#define EE   512
#define HC   128          // H chunk size
#define NCH  (HH/HC)      // 8 chunks

typedef __attribute__((ext_vector_type(16))) float f32x16;   // 32x32 MFMA accumulator
typedef __attribute__((ext_vector_type(8)))  int   int8v;    // 32B f8f6f4 operand (8 VGPRs)

#define W1SCALE 32.0f     // W1 pre-scaled into e4m3 range; undone in pack_h bias-add
#define W2SCALE 32.0f     // W2 pre-scaled into e4m3 range; undone in epilogue

// LDS layout (fp8 era, MX gemm2):
//   Xs: [64][256B] fp8, offset 0, XOR-swizzled 8B granule      (16 KiB)
//   Hs: [64] rows, 144B stride (128 data + 16 pad), 2 buffers  (2 x 9216 B)
//   Bs: b1 copy, 1024 f32                                       (4 KiB)
#define XS_OFF 0
#define HS_OFF 16384
#define HSTRIDE 144
#define HBUF  9216
#define BS_OFF 34816
#define LDS_TOT 38912

// Prep: weights in per-lane MFMA fragment order, fp8 e4m3.
//   w1f8 (8B/lane, K=16 frags): frag f = ((blk*16 + ks)*64 + lane), lane = g5*32+l31:
//       byte j = fp8(32*W1[(ks*16 + g5*8 + j)][blk*32 + l31])       (32768 frags, 256 KiB)
//   w2mx (32B/lane, K=64 frags): frag f = ((eblk*8 + hc)*2 + kk)*64 + lane:
//       byte j (0..31) = fp8(32*W2[(hc*128 + kk*64 + g5*32 + j)][eblk*32 + l31])
//       (256 frags x 2 KiB = 512 KiB)
__global__ void prep_weights(const float* __restrict__ W1, const float* __restrict__ W2,
                             int* __restrict__ w1f8, int* __restrict__ w2mx) {
    int g = blockIdx.x * 512 + threadIdx.x;      // 96 blocks * 512 = 49152 exactly
    if (g < 32768) {
        int f   = g;
        int l31 = f & 31;
        int g5  = (f >> 5) & 1;
        int ks  = (f >> 6) & 15;
        int blk = f >> 10;                        // 0..31
        int h   = blk * 32 + l31;
        int d0  = ks * 16 + g5 * 8;
        float t[8];
        #pragma unroll
        for (int j = 0; j < 8; ++j) t[j] = W1[(size_t)(d0 + j) * HH + h] * W1SCALE;
        int lo = __builtin_amdgcn_cvt_pk_fp8_f32(t[0], t[1], 0, false);
        lo     = __builtin_amdgcn_cvt_pk_fp8_f32(t[2], t[3], lo, true);
        int hi = __builtin_amdgcn_cvt_pk_fp8_f32(t[4], t[5], 0, false);
        hi     = __builtin_amdgcn_cvt_pk_fp8_f32(t[6], t[7], hi, true);
        w1f8[(size_t)f * 2]     = lo;
        w1f8[(size_t)f * 2 + 1] = hi;
    } else {
        int f    = g - 32768;                     // 0..16383
        int l31  = f & 31;
        int g5   = (f >> 5) & 1;
        int kk   = (f >> 6) & 1;
        int hc   = (f >> 7) & 7;
        int eblk = f >> 10;                       // 0..15
        int e    = eblk * 32 + l31;
        int k0   = hc * 128 + kk * 64 + g5 * 32;
        int* dst = w2mx + ((size_t)(((eblk * 8 + hc) * 2 + kk) * 64 + g5 * 32 + l31)) * 8;
        #pragma unroll
        for (int q = 0; q < 8; ++q) {
            float t0 = W2[(size_t)(k0 + 4 * q + 0) * EE + e] * W2SCALE;
            float t1 = W2[(size_t)(k0 + 4 * q + 1) * EE + e] * W2SCALE;
            float t2 = W2[(size_t)(k0 + 4 * q + 2) * EE + e] * W2SCALE;
            float t3 = W2[(size_t)(k0 + 4 * q + 3) * EE + e] * W2SCALE;
            int pk = __builtin_amdgcn_cvt_pk_fp8_f32(t0, t1, 0, false);
            pk     = __builtin_amdgcn_cvt_pk_fp8_f32(t2, t3, pk, true);
            dst[q] = pk;
        }
    }
}

// Fused: per-batch MLP + leave-one-out mean pooling + concat.
// grid = 2048 (one WG per batch), block = 512 (8 waves), 2 blocks/CU.
// GEMM1: fp8 K=16 MFMA. GEMM2: MX-scaled K=64 f8f6f4 MFMA (scales = 1.0).
__global__ __launch_bounds__(512, 4)
void fused_mlp_loo(const float* __restrict__ X,
                   const long long* __restrict__ w1f8,   // fragment-ordered W1^T fp8 (x32)
                   const int8v* __restrict__ w2mx,       // fragment-ordered W2^T fp8 K=64 (x32)
                   const float* __restrict__ b1,
                   const float* __restrict__ b2,
                   float* __restrict__ out)
{
    __shared__ __attribute__((aligned(16))) unsigned char lds[LDS_TOT];

    const int bid = blockIdx.x;
    const int tid = threadIdx.x;
    const int w   = tid >> 6;    // wave 0..7
    const int l   = tid & 63;
    const int g5  = l >> 5;      // 0/1
    const int l31 = l & 31;
    const int wh  = w >> 1;      // GEMM1 hcol group 0..3
    const int wx  = w & 1;       // GEMM1 xrow group 0..1

    // ---- stage b1 into LDS ----
    {
        float2 v = *(const float2*)(b1 + tid * 2);
        *(float2*)(lds + BS_OFF + tid * 8) = v;
    }
    // ---- stage X (f32 -> fp8, XOR-swizzled) + copy inputs to out[..., 0:256] ----
    {
        const float4* Xv = (const float4*)(X + (size_t)bid * (NN * DD));
        #pragma unroll
        for (int k = 0; k < 8; ++k) {
            int f = tid + k * 512;           // float4 index in [0,4096)
            float4 v = Xv[f];                // fully coalesced
            int row = f >> 6;                // 0..63
            int c4  = f & 63;                // float4 within row
            int pk = __builtin_amdgcn_cvt_pk_fp8_f32(v.x, v.y, 0, false);
            pk     = __builtin_amdgcn_cvt_pk_fp8_f32(v.z, v.w, pk, true);
            int off = (c4 * 4) ^ ((row & 15) << 3);
            *(int*)(lds + XS_OFF + row * 256 + off) = pk;
            float4* ov = (float4*)(out + (size_t)(bid * NN + row) * (DD + EE));
            ov[c4] = v;                      // input copy (exact f32)
        }
    }
    __syncthreads();

    const int xrow = 32 * wx + l31;
    const unsigned char* xbase = lds + XS_OFF + xrow * 256;
    const int xswz = (xrow & 15) << 3;

    f32x16 acc[2][2] = {};   // emb accumulators (scaled x32): rows 0..63 x cols [64w, 64w+64)

    // GEMM1 for chunk hc: c1 = 32 * h^T chunk (A = w1f8 frag, B = Xs frag), fp8 K=16
    auto gemm1_compute = [&](int hc, f32x16& c1) {
        const long long* a1p = w1f8 + (size_t)((hc * 4 + wh) * 16) * 64 + l;
        #pragma unroll
        for (int ks = 0; ks < 16; ++ks) {
            long long a1 = a1p[ks * 64];   // contiguous 512B wave burst
            long long xb = *(const long long*)(xbase + ((ks * 16 + 8 * g5) ^ xswz));
            c1 = __builtin_amdgcn_mfma_f32_32x32x16_fp8_fp8(a1, xb, c1, 0, 0, 0);
        }
    };

    // bias + relu + pack h chunk into Hs[hc&1] as fp8 (padded 144B rows, no swizzle).
    auto pack_h = [&](int hc, const f32x16& c1) {
        unsigned char* hbase = lds + HS_OFF + (hc & 1) * HBUF + xrow * HSTRIDE;
        const float* Bs = (const float*)(lds + BS_OFF);
        const float is = 1.0f / W1SCALE;
        #pragma unroll
        for (int q = 0; q < 4; ++q) {
            float4 bb = *(const float4*)(Bs + hc * HC + 32 * wh + 4 * g5 + 8 * q);
            float v0 = fmaxf(fmaf(c1[4 * q + 0], is, bb.x), 0.f);
            float v1 = fmaxf(fmaf(c1[4 * q + 1], is, bb.y), 0.f);
            float v2 = fmaxf(fmaf(c1[4 * q + 2], is, bb.z), 0.f);
            float v3 = fmaxf(fmaf(c1[4 * q + 3], is, bb.w), 0.f);
            int pk = __builtin_amdgcn_cvt_pk_fp8_f32(v0, v1, 0, false);
            pk     = __builtin_amdgcn_cvt_pk_fp8_f32(v2, v3, pk, true);
            *(int*)(hbase + 32 * wh + 8 * q + 4 * g5) = pk;
        }
    };

    // GEMM2 chunk hc via MX K=64: acc += Hs[hc&1] @ w2mx[chunk,:], scales = 1.0
    auto gemm2_step = [&](int hc) {
        const unsigned char* hrd = lds + HS_OFF + (hc & 1) * HBUF;
        #pragma unroll
        for (int kk = 0; kk < 2; ++kk) {
            int8v a2[2];
            #pragma unroll
            for (int mf = 0; mf < 2; ++mf) {
                const unsigned char* ap = hrd + (32 * mf + l31) * HSTRIDE + kk * 64 + 32 * g5;
                int4 lo = *(const int4*)(ap);
                int4 hi = *(const int4*)(ap + 16);
                int8v a;
                a[0] = lo.x; a[1] = lo.y; a[2] = lo.z; a[3] = lo.w;
                a[4] = hi.x; a[5] = hi.y; a[6] = hi.z; a[7] = hi.w;
                a2[mf] = a;
            }
            {
                int8v bw0 = w2mx[(size_t)(((2 * w + 0) * 8 + hc) * 2 + kk) * 64 + l];
                acc[0][0] = __builtin_amdgcn_mfma_scale_f32_32x32x64_f8f6f4(
                                a2[0], bw0, acc[0][0], 0, 0, 0, 0x7F, 0, 0x7F);
                acc[1][0] = __builtin_amdgcn_mfma_scale_f32_32x32x64_f8f6f4(
                                a2[1], bw0, acc[1][0], 0, 0, 0, 0x7F, 0, 0x7F);
            }
            {
                int8v bw1 = w2mx[(size_t)(((2 * w + 1) * 8 + hc) * 2 + kk) * 64 + l];
                acc[0][1] = __builtin_amdgcn_mfma_scale_f32_32x32x64_f8f6f4(
                                a2[0], bw1, acc[0][1], 0, 0, 0, 0x7F, 0, 0x7F);
                acc[1][1] = __builtin_amdgcn_mfma_scale_f32_32x32x64_f8f6f4(
                                a2[1], bw1, acc[1][1], 0, 0, 0, 0x7F, 0, 0x7F);
            }
        }
    };

    // ---- software-pipelined main loop: one barrier per chunk ----
    {
        f32x16 c1 = {};
        gemm1_compute(0, c1);
        pack_h(0, c1);
    }
    __syncthreads();

    for (int i = 0; i < NCH - 1; ++i) {
        // produce chunk i+1 (long-latency weight loads) interleaved with consuming chunk i
        f32x16 c1 = {};
        gemm1_compute(i + 1, c1);
        gemm2_step(i);
        pack_h(i + 1, c1);
        __syncthreads();
    }
    gemm2_step(NCH - 1);

    // ---- epilogue: in-register LOO (acc carries x32 scale from W2; undo here) ----
    float tsum[2];
    #pragma unroll
    for (int nf = 0; nf < 2; ++nf) {
        float s = 0.f;
        #pragma unroll
        for (int mf = 0; mf < 2; ++mf)
            #pragma unroll
            for (int r = 0; r < 16; ++r)
                s += acc[mf][nf][r];
        s += __shfl_xor(s, 32, 64);    // combine the two lane halves -> full 64-row column sum
        tsum[nf] = s;
    }
    const float b2c0 = b2[64 * w + l31];
    const float b2c1 = b2[64 * w + 32 + l31];
    const float sc = 1.0f / (63.0f * W2SCALE);
    float* obase = out + (size_t)bid * NN * (DD + EE) + DD;
    #pragma unroll
    for (int mf = 0; mf < 2; ++mf) {
        #pragma unroll
        for (int r = 0; r < 16; ++r) {
            int row = 32 * mf + (r & 3) + 8 * (r >> 2) + 4 * g5;
            float* orow = obase + (size_t)row * (DD + EE);
            {
                float raw = acc[mf][0][r];
                orow[64 * w + l31] = (tsum[0] - raw) * sc + b2c0;
            }
            {
                float raw = acc[mf][1][r];
                orow[64 * w + 32 + l31] = (tsum[1] - raw) * sc + b2c1;
            }
        }
    }
}

extern "C" void kernel_launch(void* const* d_in, const int* in_sizes, int n_in,
                              void* d_out, int out_size, void* d_ws, size_t ws_size,
                              hipStream_t stream) {
    const float* X  = (const float*)d_in[0];
    const float* W1 = (const float*)d_in[1];
    const float* b1 = (const float*)d_in[2];
    const float* W2 = (const float*)d_in[3];
    const float* b2 = (const float*)d_in[4];
    float* out = (float*)d_out;

    int* w1f8 = (int*)d_ws;                                  // 32768 frags * 8B  = 256 KiB
    int* w2mx = w1f8 + (size_t)32768 * 2;                    // 256 frags * 2 KiB = 512 KiB

    prep_weights<<<96, 512, 0, stream>>>(W1, W2, w1f8, w2mx);
    fused_mlp_loo<<<NB_B, 512, 0, stream>>>(X, (const long long*)w1f8, (const int8v*)w2mx,
                                            b1, b2, out);
}

// Round 18
// 177.647 us; speedup vs baseline: 2.0121x; 1.4348x over previous
//
#include <hip/hip_runtime.h>
#include <hip/hip_bf16.h>
#include <stdint.h>

// Problem constants
#define NB_B 2048
#define NN   64
#define DD   256
#define HH   1024
#define EE   512
#define HC   128          // H chunk size
#define NCH  (HH/HC)      // 8 chunks

typedef __attribute__((ext_vector_type(16))) float f32x16;   // 32x32 MFMA accumulator
typedef __attribute__((ext_vector_type(8)))  int   int8v;    // 32B f8f6f4 operand (8 VGPRs)

#define W1SCALE 32.0f     // W1 pre-scaled into e4m3 range; undone in pack_h bias-add
#define W2SCALE 32.0f     // W2 pre-scaled into e4m3 range; undone in epilogue

// LDS layout (all-MX era):
//   Xs: [64] rows, 272B stride (256 fp8 data + 16 pad), plain row-major (17 KiB)
//   Hs: [64] rows, 144B stride (128 data + 16 pad), 2 buffers  (2 x 9216 B)
//   Bs: b1 copy, 1024 f32                                       (4 KiB)
#define XS_OFF 0
#define XSTRIDE 272
#define HS_OFF 17408
#define HSTRIDE 144
#define HBUF  9216
#define BS_OFF 35840
#define LDS_TOT 39936

// Prep: weights in per-lane K=64 MX fragment order, fp8 e4m3, 32B/lane.
//   w1mx: frag f = ((hc*4 + wh)*4 + kk)*64 + g5*32 + l31:
//       byte j (0..31) = fp8(32*W1[(kk*64 + g5*32 + j)][hc*128 + wh*32 + l31])
//       (8192 frags x 32B = 256 KiB)
//   w2mx: frag f = ((eblk*8 + hc)*2 + kk)*64 + g5*32 + l31:
//       byte j (0..31) = fp8(32*W2[(hc*128 + kk*64 + g5*32 + j)][eblk*32 + l31])
//       (16384 frags x 32B = 512 KiB)
__global__ void prep_weights(const float* __restrict__ W1, const float* __restrict__ W2,
                             int* __restrict__ w1mx, int* __restrict__ w2mx) {
    int g = blockIdx.x * 512 + threadIdx.x;      // 48 blocks * 512 = 24576 exactly
    if (g < 8192) {
        int f   = g;
        int l31 = f & 31;
        int g5  = (f >> 5) & 1;
        int kk  = (f >> 6) & 3;
        int wh  = (f >> 8) & 3;
        int hc  = f >> 10;                        // 0..7
        int h   = hc * 128 + wh * 32 + l31;
        int d0  = kk * 64 + g5 * 32;
        int* dst = w1mx + (size_t)f * 8;
        #pragma unroll
        for (int q = 0; q < 8; ++q) {
            float t0 = W1[(size_t)(d0 + 4 * q + 0) * HH + h] * W1SCALE;
            float t1 = W1[(size_t)(d0 + 4 * q + 1) * HH + h] * W1SCALE;
            float t2 = W1[(size_t)(d0 + 4 * q + 2) * HH + h] * W1SCALE;
            float t3 = W1[(size_t)(d0 + 4 * q + 3) * HH + h] * W1SCALE;
            int pk = __builtin_amdgcn_cvt_pk_fp8_f32(t0, t1, 0, false);
            pk     = __builtin_amdgcn_cvt_pk_fp8_f32(t2, t3, pk, true);
            dst[q] = pk;
        }
    } else {
        int f    = g - 8192;                      // 0..16383
        int l31  = f & 31;
        int g5   = (f >> 5) & 1;
        int kk   = (f >> 6) & 1;
        int hc   = (f >> 7) & 7;
        int eblk = f >> 10;                       // 0..15
        int e    = eblk * 32 + l31;
        int k0   = hc * 128 + kk * 64 + g5 * 32;
        int* dst = w2mx + (size_t)f * 8;
        #pragma unroll
        for (int q = 0; q < 8; ++q) {
            float t0 = W2[(size_t)(k0 + 4 * q + 0) * EE + e] * W2SCALE;
            float t1 = W2[(size_t)(k0 + 4 * q + 1) * EE + e] * W2SCALE;
            float t2 = W2[(size_t)(k0 + 4 * q + 2) * EE + e] * W2SCALE;
            float t3 = W2[(size_t)(k0 + 4 * q + 3) * EE + e] * W2SCALE;
            int pk = __builtin_amdgcn_cvt_pk_fp8_f32(t0, t1, 0, false);
            pk     = __builtin_amdgcn_cvt_pk_fp8_f32(t2, t3, pk, true);
            dst[q] = pk;
        }
    }
}

// Fused: per-batch MLP + leave-one-out mean pooling + concat.
// grid = 2048 (one WG per batch), block = 512 (8 waves), 2 blocks/CU.
// Both GEMMs via MX-scaled K=64 f8f6f4 MFMA (fp8 e4m3, scales = 1.0).
__global__ __launch_bounds__(512, 4)
void fused_mlp_loo(const float* __restrict__ X,
                   const int8v* __restrict__ w1mx,       // fragment-ordered W1^T fp8 K=64 (x32)
                   const int8v* __restrict__ w2mx,       // fragment-ordered W2^T fp8 K=64 (x32)
                   const float* __restrict__ b1,
                   const float* __restrict__ b2,
                   float* __restrict__ out)
{
    __shared__ __attribute__((aligned(16))) unsigned char lds[LDS_TOT];

    const int bid = blockIdx.x;
    const int tid = threadIdx.x;
    const int w   = tid >> 6;    // wave 0..7
    const int l   = tid & 63;
    const int g5  = l >> 5;      // 0/1
    const int l31 = l & 31;
    const int wh  = w >> 1;      // GEMM1 hcol group 0..3
    const int wx  = w & 1;       // GEMM1 xrow group 0..1

    // ---- stage b1 into LDS ----
    {
        float2 v = *(const float2*)(b1 + tid * 2);
        *(float2*)(lds + BS_OFF + tid * 8) = v;
    }
    // ---- stage X (f32 -> fp8, plain padded row-major) + copy inputs to out[..., 0:256] ----
    {
        const float4* Xv = (const float4*)(X + (size_t)bid * (NN * DD));
        #pragma unroll
        for (int k = 0; k < 8; ++k) {
            int f = tid + k * 512;           // float4 index in [0,4096)
            float4 v = Xv[f];                // fully coalesced
            int row = f >> 6;                // 0..63
            int c4  = f & 63;                // float4 within row
            int pk = __builtin_amdgcn_cvt_pk_fp8_f32(v.x, v.y, 0, false);
            pk     = __builtin_amdgcn_cvt_pk_fp8_f32(v.z, v.w, pk, true);
            *(int*)(lds + XS_OFF + row * XSTRIDE + c4 * 4) = pk;
            float4* ov = (float4*)(out + (size_t)(bid * NN + row) * (DD + EE));
            ov[c4] = v;                      // input copy (exact f32)
        }
    }
    __syncthreads();

    const int xrow = 32 * wx + l31;

    f32x16 acc[2][2] = {};   // emb accumulators (scaled x32): rows 0..63 x cols [64w, 64w+64)

    // GEMM1 for chunk hc via MX K=64: c1 = 32 * h^T chunk (A = w1mx, B = Xs rows)
    auto gemm1_compute = [&](int hc, f32x16& c1) {
        const int8v* a1p = w1mx + (size_t)((hc * 4 + wh) * 4) * 64 + l;
        const unsigned char* xp0 = lds + XS_OFF + xrow * XSTRIDE + 32 * g5;
        #pragma unroll
        for (int kk = 0; kk < 4; ++kk) {
            int8v a1 = a1p[kk * 64];       // contiguous 2 KiB wave burst
            const unsigned char* xp = xp0 + kk * 64;
            int4 lo = *(const int4*)(xp);
            int4 hi = *(const int4*)(xp + 16);
            int8v xb;
            xb[0] = lo.x; xb[1] = lo.y; xb[2] = lo.z; xb[3] = lo.w;
            xb[4] = hi.x; xb[5] = hi.y; xb[6] = hi.z; xb[7] = hi.w;
            c1 = __builtin_amdgcn_mfma_scale_f32_32x32x64_f8f6f4(
                     a1, xb, c1, 0, 0, 0, 0x7F, 0, 0x7F);
        }
    };

    // bias + relu + pack h chunk into Hs[hc&1] as fp8 (padded 144B rows).
    auto pack_h = [&](int hc, const f32x16& c1) {
        unsigned char* hbase = lds + HS_OFF + (hc & 1) * HBUF + xrow * HSTRIDE;
        const float* Bs = (const float*)(lds + BS_OFF);
        const float is = 1.0f / W1SCALE;
        #pragma unroll
        for (int q = 0; q < 4; ++q) {
            float4 bb = *(const float4*)(Bs + hc * HC + 32 * wh + 4 * g5 + 8 * q);
            float v0 = fmaxf(fmaf(c1[4 * q + 0], is, bb.x), 0.f);
            float v1 = fmaxf(fmaf(c1[4 * q + 1], is, bb.y), 0.f);
            float v2 = fmaxf(fmaf(c1[4 * q + 2], is, bb.z), 0.f);
            float v3 = fmaxf(fmaf(c1[4 * q + 3], is, bb.w), 0.f);
            int pk = __builtin_amdgcn_cvt_pk_fp8_f32(v0, v1, 0, false);
            pk     = __builtin_amdgcn_cvt_pk_fp8_f32(v2, v3, pk, true);
            *(int*)(hbase + 32 * wh + 8 * q + 4 * g5) = pk;
        }
    };

    // GEMM2 chunk hc via MX K=64: acc += Hs[hc&1] @ w2mx[chunk,:], scales = 1.0
    auto gemm2_step = [&](int hc) {
        const unsigned char* hrd = lds + HS_OFF + (hc & 1) * HBUF;
        #pragma unroll
        for (int kk = 0; kk < 2; ++kk) {
            int8v a2[2];
            #pragma unroll
            for (int mf = 0; mf < 2; ++mf) {
                const unsigned char* ap = hrd + (32 * mf + l31) * HSTRIDE + kk * 64 + 32 * g5;
                int4 lo = *(const int4*)(ap);
                int4 hi = *(const int4*)(ap + 16);
                int8v a;
                a[0] = lo.x; a[1] = lo.y; a[2] = lo.z; a[3] = lo.w;
                a[4] = hi.x; a[5] = hi.y; a[6] = hi.z; a[7] = hi.w;
                a2[mf] = a;
            }
            {
                int8v bw0 = w2mx[(size_t)(((2 * w + 0) * 8 + hc) * 2 + kk) * 64 + l];
                acc[0][0] = __builtin_amdgcn_mfma_scale_f32_32x32x64_f8f6f4(
                                a2[0], bw0, acc[0][0], 0, 0, 0, 0x7F, 0, 0x7F);
                acc[1][0] = __builtin_amdgcn_mfma_scale_f32_32x32x64_f8f6f4(
                                a2[1], bw0, acc[1][0], 0, 0, 0, 0x7F, 0, 0x7F);
            }
            {
                int8v bw1 = w2mx[(size_t)(((2 * w + 1) * 8 + hc) * 2 + kk) * 64 + l];
                acc[0][1] = __builtin_amdgcn_mfma_scale_f32_32x32x64_f8f6f4(
                                a2[0], bw1, acc[0][1], 0, 0, 0, 0x7F, 0, 0x7F);
                acc[1][1] = __builtin_amdgcn_mfma_scale_f32_32x32x64_f8f6f4(
                                a2[1], bw1, acc[1][1], 0, 0, 0, 0x7F, 0, 0x7F);
            }
        }
    };

    // ---- software-pipelined main loop: one barrier per chunk ----
    {
        f32x16 c1 = {};
        gemm1_compute(0, c1);
        pack_h(0, c1);
    }
    __syncthreads();

    for (int i = 0; i < NCH - 1; ++i) {
        // produce chunk i+1 (long-latency weight loads) interleaved with consuming chunk i
        f32x16 c1 = {};
        gemm1_compute(i + 1, c1);
        gemm2_step(i);
        pack_h(i + 1, c1);
        __syncthreads();
    }
    gemm2_step(NCH - 1);

    // ---- epilogue: in-register LOO (acc carries x32 scale from W2; undo here) ----
    float tsum[2];
    #pragma unroll
    for (int nf = 0; nf < 2; ++nf) {
        float s = 0.f;
        #pragma unroll
        for (int mf = 0; mf < 2; ++mf)
            #pragma unroll
            for (int r = 0; r < 16; ++r)
                s += acc[mf][nf][r];
        s += __shfl_xor(s, 32, 64);    // combine the two lane halves -> full 64-row column sum
        tsum[nf] = s;
    }
    const float b2c0 = b2[64 * w + l31];
    const float b2c1 = b2[64 * w + 32 + l31];
    const float sc = 1.0f / (63.0f * W2SCALE);
    float* obase = out + (size_t)bid * NN * (DD + EE) + DD;
    #pragma unroll
    for (int mf = 0; mf < 2; ++mf) {
        #pragma unroll
        for (int r = 0; r < 16; ++r) {
            int row = 32 * mf + (r & 3) + 8 * (r >> 2) + 4 * g5;
            float* orow = obase + (size_t)row * (DD + EE);
            {
                float raw = acc[mf][0][r];
                orow[64 * w + l31] = (tsum[0] - raw) * sc + b2c0;
            }
            {
                float raw = acc[mf][1][r];
                orow[64 * w + 32 + l31] = (tsum[1] - raw) * sc + b2c1;
            }
        }
    }
}

extern "C" void kernel_launch(void* const* d_in, const int* in_sizes, int n_in,
                              void* d_out, int out_size, void* d_ws, size_t ws_size,
                              hipStream_t stream) {
    const float* X  = (const float*)d_in[0];
    const float* W1 = (const float*)d_in[1];
    const float* b1 = (const float*)d_in[2];
    const float* W2 = (const float*)d_in[3];
    const float* b2 = (const float*)d_in[4];
    float* out = (float*)d_out;

    int* w1mx = (int*)d_ws;                                  // 8192 frags * 32B  = 256 KiB
    int* w2mx = w1mx + (size_t)8192 * 8;                     // 16384 frags * 32B = 512 KiB

    prep_weights<<<48, 512, 0, stream>>>(W1, W2, w1mx, w2mx);
    fused_mlp_loo<<<NB_B, 512, 0, stream>>>(X, (const int8v*)w1mx, (const int8v*)w2mx,
                                            b1, b2, out);
}